// Round 7
// baseline (414.497 us; speedup 1.0000x reference)
//
#include <hip/hip_runtime.h>

#define HASH_BINS 100000
#define EMBD 64
#define BATCH 262144
#define BM 64
#define SA 264  // act buffer A stride (bf16 elems)
#define SB 232  // act buffer B stride (bf16 elems)

typedef __attribute__((ext_vector_type(8))) short short8;
typedef __attribute__((ext_vector_type(4))) float floatx4;
typedef __attribute__((ext_vector_type(4))) unsigned short ushortx4;

static __device__ __forceinline__ unsigned short f2bf(float f) {
  unsigned u = __builtin_bit_cast(unsigned, f);
  u += 0x7fff + ((u >> 16) & 1);  // round-to-nearest-even
  return (unsigned short)(u >> 16);
}
static __device__ __forceinline__ float bf2f(unsigned short b) {
  return __builtin_bit_cast(float, ((unsigned)b) << 16);
}

// ---------------- prep: build bf16 transposed/padded weights in ws ----------------
// ws layout (bytes):
//   0      : S   fp32 [128]            (rowsum of cross_k^2)
//   512    : Kt  bf16 [128][128]       (cross_k transposed)   } contiguous => combined
//   33280  : W1t bf16 [224][128]       (W1 transposed, N-pad) } [352][128] matrix
//   90624  : W2t bf16 [256][224]       (K-pad 200->224)
//   205312 : W3t bf16 [224][256]       (N-pad 200->224)
//   320000 : W4t bf16 [128][224]       (K-pad 200->224)
__global__ void dfm_prep(const float* __restrict__ K, const float* __restrict__ W1,
                         const float* __restrict__ W2, const float* __restrict__ W3,
                         const float* __restrict__ W4,
                         float* __restrict__ S, unsigned short* __restrict__ Kt,
                         unsigned short* __restrict__ W1t, unsigned short* __restrict__ W2t,
                         unsigned short* __restrict__ W3t, unsigned short* __restrict__ W4t)
{
  int idx = blockIdx.x * 256 + threadIdx.x;
  if (idx < 128) {
    float s = 0.f;
    for (int j = 0; j < 128; j++) { float v = K[idx * 128 + j]; s += v * v; }
    S[idx] = s;
  }
  int i = idx;
  if (i < 16384) {                        // Kt[n][k] = K[k][n]; i over source K
    int k = i >> 7, n = i & 127;
    Kt[n * 128 + k] = f2bf(K[i]);
  } else if ((i -= 16384) < 25600) {      // W1t[n][k] = W1[k][n]; i over source W1 [128][200]
    int k = i / 200, n = i - k * 200;
    W1t[n * 128 + k] = f2bf(W1[i]);
  } else if ((i -= 25600) < 3072) {       // W1t zero rows n in [200,224)
    int n = 200 + (i >> 7), k = i & 127;
    W1t[n * 128 + k] = 0;
  } else if ((i -= 3072) < 51200) {       // W2t[n][k] = W2[k][n]; source W2 [200][256]
    int k = i >> 8, n = i & 255;
    W2t[n * 224 + k] = f2bf(W2[i]);
  } else if ((i -= 51200) < 6144) {       // W2t zero k in [200,224), n in [0,256)
    int n = i / 24, k = 200 + (i - n * 24);
    W2t[n * 224 + k] = 0;
  } else if ((i -= 6144) < 51200) {       // W3t[n][k] = W3[k][n]; source W3 [256][200]
    int k = i / 200, n = i - k * 200;
    W3t[n * 256 + k] = f2bf(W3[i]);
  } else if ((i -= 51200) < 6144) {       // W3t zero rows n in [200,224)
    int n = 200 + (i >> 8), k = i & 255;
    W3t[n * 256 + k] = 0;
  } else if ((i -= 6144) < 25600) {       // W4t[n][k] = W4[k][n]; source W4 [200][128]
    int k = i >> 7, n = i & 127;
    W4t[n * 224 + k] = f2bf(W4[i]);
  } else if ((i -= 25600) < 3072) {       // W4t zero k in [200,224), n in [0,128)
    int n = i / 24, k = 200 + (i - n * 24);
    W4t[n * 224 + k] = 0;
  }
}

// ---- MFMA pass: CH col-tiles x 2 row-tiles (rows rbase..rbase+31), K=KP ----
// Operand order: mfma(wt, act, acc) => lane (m,qd,reg) holds
// D[neuron = tile*16 + qd*4 + reg][data row = rbase + rt*16 + m].
template <int KP, int CH>
static __device__ __forceinline__ void mfma_pass(const unsigned short* __restrict__ wt,
                                                 int tileRow0, const unsigned short* actIn,
                                                 int sin, int rbase, int m, int qd,
                                                 floatx4* acc)
{
#pragma unroll
  for (int i = 0; i < CH * 2; i++) acc[i] = {0.f, 0.f, 0.f, 0.f};
#pragma unroll
  for (int ks = 0; ks < KP / 32; ks++) {
    short8 a0 = *(const short8*)&actIn[(rbase + m) * sin + ks * 32 + qd * 8];
    short8 a1 = *(const short8*)&actIn[(rbase + 16 + m) * sin + ks * 32 + qd * 8];
#pragma unroll
    for (int n = 0; n < CH; n++) {
      short8 w = *(const short8*)&wt[(tileRow0 + n * 16 + m) * KP + ks * 32 + qd * 8];
      acc[n * 2 + 0] = __builtin_amdgcn_mfma_f32_16x16x32_bf16(w, a0, acc[n * 2 + 0], 0, 0, 0);
      acc[n * 2 + 1] = __builtin_amdgcn_mfma_f32_16x16x32_bf16(w, a1, acc[n * 2 + 1], 0, 0, 0);
    }
  }
}

// ---- epilogue: bias + relu, packed 8B stores (4 consecutive cols per lane) ----
template <int CH>
static __device__ __forceinline__ void epilogue_relu(const float* __restrict__ bias,
                                                     int colBase, int nreal,
                                                     unsigned short* actOut, int sout,
                                                     int rbase, int m, int qd,
                                                     const floatx4* acc)
{
#pragma unroll
  for (int n = 0; n < CH; n++) {
    int col = colBase + n * 16 + qd * 4;
    float b0 = 0.f, b1 = 0.f, b2 = 0.f, b3 = 0.f;
    if (col < nreal) {  // nreal % 4 == 0, col % 4 == 0 -> uniform per lane
      float4 q = *(const float4*)(bias + col);
      b0 = q.x; b1 = q.y; b2 = q.z; b3 = q.w;
    }
#pragma unroll
    for (int rt = 0; rt < 2; rt++) {
      ushortx4 h = { f2bf(fmaxf(acc[n * 2 + rt][0] + b0, 0.f)),
                     f2bf(fmaxf(acc[n * 2 + rt][1] + b1, 0.f)),
                     f2bf(fmaxf(acc[n * 2 + rt][2] + b2, 0.f)),
                     f2bf(fmaxf(acc[n * 2 + rt][3] + b3, 0.f)) };
      *(ushortx4*)&actOut[(rbase + rt * 16 + m) * sout + col] = h;
    }
  }
}

// ---------------- fused main kernel ----------------
// 8 waves = 2 row-groups (32 rows each) x 4 col-groups: halves per-block LDS
// activation reads vs all-rows-per-wave; weight fragments read by 2 waves (L2-cheap).
__global__ __launch_bounds__(512)
void dfm_main(const int* __restrict__ uidx, const int* __restrict__ iidx,
              const float* __restrict__ uemb, const float* __restrict__ iemb,
              const float* __restrict__ linw, const float* __restrict__ linb,
              const float* __restrict__ b1, const float* __restrict__ b2,
              const float* __restrict__ b3, const float* __restrict__ b4,
              const float* __restrict__ W5, const float* __restrict__ b5,
              const float* __restrict__ S, const unsigned short* __restrict__ Wc,
              const unsigned short* __restrict__ W2t, const unsigned short* __restrict__ W3t,
              const unsigned short* __restrict__ W4t,
              float* __restrict__ out)
{
  __shared__ unsigned short actA[BM * SA];
  __shared__ unsigned short actB[BM * SB];
  __shared__ float crosspart[2][BM];
  __shared__ float part[BM][8];
  __shared__ float linrow[BM];

  const int t = threadIdx.x;
  const int lane = t & 63, wave = t >> 6;
  const int m = lane & 15, qd = lane >> 4;
  const int rg = wave >> 2, cg = wave & 3;
  const int rbase = rg * 32;
  const int r = t >> 3, c = t & 7;  // gather/final mapping: 8 threads per row

  // ---- gather + linear + q-partials (q = sum x^2 * rowsum(K^2)) ----
  {
    int g = blockIdx.x * BM + r;
    int u = uidx[g], it = iidx[g];
    const float* up = uemb + (long)u * EMBD + c * 8;
    const float* ip = iemb + (long)it * EMBD + c * 8;
    float qp = 0.f;
#pragma unroll
    for (int j = 0; j < 8; j += 4) {
      float4 f = *(const float4*)(up + j);
      int col = c * 8 + j;
      float4 sv = *(const float4*)(S + col);
      ushortx4 h = {f2bf(f.x), f2bf(f.y), f2bf(f.z), f2bf(f.w)};
      *(ushortx4*)&actA[r * SA + col] = h;
      qp += f.x * f.x * sv.x + f.y * f.y * sv.y + f.z * f.z * sv.z + f.w * f.w * sv.w;
    }
#pragma unroll
    for (int j = 0; j < 8; j += 4) {
      float4 f = *(const float4*)(ip + j);
      int col = 64 + c * 8 + j;
      float4 sv = *(const float4*)(S + col);
      ushortx4 h = {f2bf(f.x), f2bf(f.y), f2bf(f.z), f2bf(f.w)};
      *(ushortx4*)&actA[r * SA + col] = h;
      qp += f.x * f.x * sv.x + f.y * f.y * sv.y + f.z * f.z * sv.z + f.w * f.w * sv.w;
    }
    part[r][c] = qp;
    if (c == 0) linrow[r] = linw[u] + linw[HASH_BINS + it] + linb[0];
  }
  __syncthreads();  // B1: emb in actA

  // ---- fused layer (K=128, reads actA): 22 tiles (0-7 cross, 8-21 L1) ----
  // cg0: tiles 0-5 (all cross); cg1: 6-11 (2 cross + 4 L1); cg2: 12-16; cg3: 17-21.
  if (cg == 0) {
    floatx4 acc[12];
    mfma_pass<128, 6>(Wc, 0, actA, SA, rbase, m, qd, acc);
    float s0 = 0.f, s1 = 0.f;
#pragma unroll
    for (int n = 0; n < 6; n++)
#pragma unroll
      for (int i = 0; i < 4; i++) {
        s0 += acc[n * 2 + 0][i] * acc[n * 2 + 0][i];
        s1 += acc[n * 2 + 1][i] * acc[n * 2 + 1][i];
      }
    s0 += __shfl_xor(s0, 16, 64); s0 += __shfl_xor(s0, 32, 64);
    s1 += __shfl_xor(s1, 16, 64); s1 += __shfl_xor(s1, 32, 64);
    if (qd == 0) { crosspart[0][rbase + m] = s0; crosspart[0][rbase + 16 + m] = s1; }
  } else if (cg == 1) {
    floatx4 acc[12];
    mfma_pass<128, 6>(Wc, 96, actA, SA, rbase, m, qd, acc);
    float s0 = 0.f, s1 = 0.f;
#pragma unroll
    for (int n = 0; n < 2; n++)
#pragma unroll
      for (int i = 0; i < 4; i++) {
        s0 += acc[n * 2 + 0][i] * acc[n * 2 + 0][i];
        s1 += acc[n * 2 + 1][i] * acc[n * 2 + 1][i];
      }
    s0 += __shfl_xor(s0, 16, 64); s0 += __shfl_xor(s0, 32, 64);
    s1 += __shfl_xor(s1, 16, 64); s1 += __shfl_xor(s1, 32, 64);
    if (qd == 0) { crosspart[1][rbase + m] = s0; crosspart[1][rbase + 16 + m] = s1; }
    epilogue_relu<4>(b1, 0, 200, actB, SB, rbase, m, qd, acc + 4);  // L1 tiles 8-11 -> cols 0-63
  } else if (cg == 2) {
    floatx4 acc[10];
    mfma_pass<128, 5>(Wc, 192, actA, SA, rbase, m, qd, acc);
    epilogue_relu<5>(b1, 64, 200, actB, SB, rbase, m, qd, acc);     // cols 64-143
  } else {
    floatx4 acc[10];
    mfma_pass<128, 5>(Wc, 272, actA, SA, rbase, m, qd, acc);
    epilogue_relu<5>(b1, 144, 200, actB, SB, rbase, m, qd, acc);    // cols 144-223
  }
  __syncthreads();  // B2: L1 out (224, zero-padded) in actB

  // ---- W2: K=224, actB -> actA, 16 tiles, 4 per cg ----
  {
    floatx4 acc[8];
    mfma_pass<224, 4>(W2t, cg * 64, actB, SB, rbase, m, qd, acc);
    epilogue_relu<4>(b2, cg * 64, 256, actA, SA, rbase, m, qd, acc);
  }
  __syncthreads();  // B3: W2 out (256) in actA

  // ---- W3: K=256, actA -> actB, 14 tiles {4,4,3,3} ----
  if (cg < 2) {
    floatx4 acc[8];
    mfma_pass<256, 4>(W3t, cg * 64, actA, SA, rbase, m, qd, acc);
    epilogue_relu<4>(b3, cg * 64, 200, actB, SB, rbase, m, qd, acc);
  } else {
    floatx4 acc[6];
    int s0 = 128 + (cg - 2) * 48;  // tiles 8-10 / 11-13
    mfma_pass<256, 3>(W3t, s0, actA, SA, rbase, m, qd, acc);
    epilogue_relu<3>(b3, s0, 200, actB, SB, rbase, m, qd, acc);
  }
  __syncthreads();  // B4: W3 out (224, zero-padded) in actB

  // ---- W4: K=224, actB -> actA, 8 tiles, 2 per cg ----
  {
    floatx4 acc[4];
    mfma_pass<224, 2>(W4t, cg * 32, actB, SB, rbase, m, qd, acc);
    epilogue_relu<2>(b4, cg * 32, 128, actA, SA, rbase, m, qd, acc);
  }
  __syncthreads();  // B5: W4 out (128) in actA

  // ---- final: W5 dot + cross combine + sigmoid ----
  {
    float qp = part[r][c];  // q-partial from gather phase (same thread wrote it)
    float d = 0.f;
    const unsigned short* ap = &actA[r * SA + c * 16];
#pragma unroll
    for (int j = 0; j < 2; j++) {
      short8 h = *(const short8*)(ap + j * 8);
      float4 w0 = *(const float4*)(W5 + c * 16 + j * 8);
      float4 w1 = *(const float4*)(W5 + c * 16 + j * 8 + 4);
      d += bf2f((unsigned short)h[0]) * w0.x + bf2f((unsigned short)h[1]) * w0.y +
           bf2f((unsigned short)h[2]) * w0.z + bf2f((unsigned short)h[3]) * w0.w +
           bf2f((unsigned short)h[4]) * w1.x + bf2f((unsigned short)h[5]) * w1.y +
           bf2f((unsigned short)h[6]) * w1.z + bf2f((unsigned short)h[7]) * w1.w;
    }
    const float inv = 0.5f / 128.f;
    part[r][c] = d - inv * qp;  // dnn partial minus q share of cross
    __syncthreads();
    if (c == 0) {
      float xk2 = crosspart[0][r] + crosspart[1][r];
      float dnn = part[r][0] + part[r][1] + part[r][2] + part[r][3] +
                  part[r][4] + part[r][5] + part[r][6] + part[r][7];
      float logit = linrow[r] + inv * xk2 + dnn + b5[0];
      out[blockIdx.x * BM + r] = 1.f / (1.f + expf(-logit));
    }
  }
}

extern "C" void kernel_launch(void* const* d_in, const int* in_sizes, int n_in,
                              void* d_out, int out_size, void* d_ws, size_t ws_size,
                              hipStream_t stream)
{
  const int*   uidx = (const int*)d_in[0];
  const int*   iidx = (const int*)d_in[1];
  const float* uemb = (const float*)d_in[2];
  const float* iemb = (const float*)d_in[3];
  const float* linw = (const float*)d_in[4];
  const float* linb = (const float*)d_in[5];
  const float* K    = (const float*)d_in[6];
  const float* W1   = (const float*)d_in[7];
  const float* b1   = (const float*)d_in[8];
  const float* W2   = (const float*)d_in[9];
  const float* b2   = (const float*)d_in[10];
  const float* W3   = (const float*)d_in[11];
  const float* b3   = (const float*)d_in[12];
  const float* W4   = (const float*)d_in[13];
  const float* b4   = (const float*)d_in[14];
  const float* W5   = (const float*)d_in[15];
  const float* b5   = (const float*)d_in[16];

  char* w = (char*)d_ws;
  float* S = (float*)w;
  unsigned short* Kt  = (unsigned short*)(w + 512);
  unsigned short* W1t = (unsigned short*)(w + 33280);
  unsigned short* W2t = (unsigned short*)(w + 90624);
  unsigned short* W3t = (unsigned short*)(w + 205312);
  unsigned short* W4t = (unsigned short*)(w + 320000);
  float* out = (float*)d_out;

  dfm_prep<<<736, 256, 0, stream>>>(K, W1, W2, W3, W4, S, Kt, W1t, W2t, W3t, W4t);
  dfm_main<<<BATCH / BM, 512, 0, stream>>>(uidx, iidx, uemb, iemb, linw, linb,
                                           b1, b2, b3, b4, W5, b5,
                                           S, Kt, W2t, W3t, W4t, out);
}

// Round 8
// 291.522 us; speedup vs baseline: 1.4218x; 1.4218x over previous
//
#include <hip/hip_runtime.h>

#define HASH_BINS 100000
#define EMBD 64
#define BATCH 262144
#define BM 64
#define SA 264  // act buffer A stride (bf16 elems)
#define SB 232  // act buffer B stride (bf16 elems)

typedef __attribute__((ext_vector_type(8))) short short8;
typedef __attribute__((ext_vector_type(4))) float floatx4;
typedef __attribute__((ext_vector_type(4))) unsigned short ushortx4;

static __device__ __forceinline__ unsigned short f2bf(float f) {
  unsigned u = __builtin_bit_cast(unsigned, f);
  u += 0x7fff + ((u >> 16) & 1);  // round-to-nearest-even
  return (unsigned short)(u >> 16);
}
static __device__ __forceinline__ float bf2f(unsigned short b) {
  return __builtin_bit_cast(float, ((unsigned)b) << 16);
}

// ---------------- prep: build bf16 transposed/padded weights in ws ----------------
// ws layout (bytes):
//   0      : S   fp32 [128]            (rowsum of cross_k^2)
//   512    : Kt  bf16 [128][128]       (cross_k transposed)   } contiguous => combined
//   33280  : W1t bf16 [224][128]       (W1 transposed, N-pad) } [352][128] matrix
//   90624  : W2t bf16 [256][224]       (K-pad 200->224)
//   205312 : W3t bf16 [224][256]       (N-pad 200->224)
//   320000 : W4t bf16 [128][224]       (K-pad 200->224)
__global__ void dfm_prep(const float* __restrict__ K, const float* __restrict__ W1,
                         const float* __restrict__ W2, const float* __restrict__ W3,
                         const float* __restrict__ W4,
                         float* __restrict__ S, unsigned short* __restrict__ Kt,
                         unsigned short* __restrict__ W1t, unsigned short* __restrict__ W2t,
                         unsigned short* __restrict__ W3t, unsigned short* __restrict__ W4t)
{
  int idx = blockIdx.x * 256 + threadIdx.x;
  if (idx < 128) {
    float s = 0.f;
    for (int j = 0; j < 128; j++) { float v = K[idx * 128 + j]; s += v * v; }
    S[idx] = s;
  }
  int i = idx;
  if (i < 16384) {                        // Kt[n][k] = K[k][n]; i over source K
    int k = i >> 7, n = i & 127;
    Kt[n * 128 + k] = f2bf(K[i]);
  } else if ((i -= 16384) < 25600) {      // W1t[n][k] = W1[k][n]; i over source W1 [128][200]
    int k = i / 200, n = i - k * 200;
    W1t[n * 128 + k] = f2bf(W1[i]);
  } else if ((i -= 25600) < 3072) {       // W1t zero rows n in [200,224)
    int n = 200 + (i >> 7), k = i & 127;
    W1t[n * 128 + k] = 0;
  } else if ((i -= 3072) < 51200) {       // W2t[n][k] = W2[k][n]; source W2 [200][256]
    int k = i >> 8, n = i & 255;
    W2t[n * 224 + k] = f2bf(W2[i]);
  } else if ((i -= 51200) < 6144) {       // W2t zero k in [200,224), n in [0,256)
    int n = i / 24, k = 200 + (i - n * 24);
    W2t[n * 224 + k] = 0;
  } else if ((i -= 6144) < 51200) {       // W3t[n][k] = W3[k][n]; source W3 [256][200]
    int k = i / 200, n = i - k * 200;
    W3t[n * 256 + k] = f2bf(W3[i]);
  } else if ((i -= 51200) < 6144) {       // W3t zero rows n in [200,224)
    int n = 200 + (i >> 8), k = i & 255;
    W3t[n * 256 + k] = 0;
  } else if ((i -= 6144) < 25600) {       // W4t[n][k] = W4[k][n]; source W4 [200][128]
    int k = i >> 7, n = i & 127;
    W4t[n * 224 + k] = f2bf(W4[i]);
  } else if ((i -= 25600) < 3072) {       // W4t zero k in [200,224), n in [0,128)
    int n = i / 24, k = 200 + (i - n * 24);
    W4t[n * 224 + k] = 0;
  }
}

// ---- MFMA pass: CH col-tiles x 4 row-tiles (ALL 64 rows), K=KP ----
// R6 partition (each weight fragment read by exactly ONE wave; 4 MFMAs hide
// each global weight load) + R7 operand order mfma(w, a):
// lane (m,qd,reg) holds D[neuron = tile*16 + qd*4 + reg][row = rt*16 + m].
template <int KP, int CH>
static __device__ __forceinline__ void mfma_pass(const unsigned short* __restrict__ wt,
                                                 int tileRow0, const unsigned short* actIn,
                                                 int sin, int m, int qd, floatx4* acc)
{
#pragma unroll
  for (int i = 0; i < CH * 4; i++) acc[i] = {0.f, 0.f, 0.f, 0.f};
#pragma unroll
  for (int ks = 0; ks < KP / 32; ks++) {
    short8 a[4];
#pragma unroll
    for (int rt = 0; rt < 4; rt++)
      a[rt] = *(const short8*)&actIn[(rt * 16 + m) * sin + ks * 32 + qd * 8];
#pragma unroll
    for (int n = 0; n < CH; n++) {
      short8 w = *(const short8*)&wt[(tileRow0 + n * 16 + m) * KP + ks * 32 + qd * 8];
#pragma unroll
      for (int rt = 0; rt < 4; rt++)
        acc[n * 4 + rt] = __builtin_amdgcn_mfma_f32_16x16x32_bf16(w, a[rt], acc[n * 4 + rt], 0, 0, 0);
    }
  }
}

// ---- epilogue: bias + relu, packed 8B stores (4 consecutive cols per lane) ----
template <int CH>
static __device__ __forceinline__ void epilogue_relu(const float* __restrict__ bias,
                                                     int colBase, int nreal,
                                                     unsigned short* actOut, int sout,
                                                     int m, int qd, const floatx4* acc)
{
#pragma unroll
  for (int n = 0; n < CH; n++) {
    int col = colBase + n * 16 + qd * 4;
    float b0 = 0.f, b1 = 0.f, b2 = 0.f, b3 = 0.f;
    if (col < nreal) {  // nreal % 4 == 0, col % 4 == 0 -> whole quad valid
      float4 q = *(const float4*)(bias + col);
      b0 = q.x; b1 = q.y; b2 = q.z; b3 = q.w;
    }
#pragma unroll
    for (int rt = 0; rt < 4; rt++) {
      ushortx4 h = { f2bf(fmaxf(acc[n * 4 + rt][0] + b0, 0.f)),
                     f2bf(fmaxf(acc[n * 4 + rt][1] + b1, 0.f)),
                     f2bf(fmaxf(acc[n * 4 + rt][2] + b2, 0.f)),
                     f2bf(fmaxf(acc[n * 4 + rt][3] + b3, 0.f)) };
      *(ushortx4*)&actOut[(rt * 16 + m) * sout + col] = h;
    }
  }
}

// ---------------- fused main kernel ----------------
// 8 waves; each wave computes ALL 64 rows x 1/8 of the output tiles (R6 partition),
// with operand-swapped MFMA + packed epilogue stores (R7's orthogonal wins).
__global__ __launch_bounds__(512)
void dfm_main(const int* __restrict__ uidx, const int* __restrict__ iidx,
              const float* __restrict__ uemb, const float* __restrict__ iemb,
              const float* __restrict__ linw, const float* __restrict__ linb,
              const float* __restrict__ b1, const float* __restrict__ b2,
              const float* __restrict__ b3, const float* __restrict__ b4,
              const float* __restrict__ W5, const float* __restrict__ b5,
              const float* __restrict__ S, const unsigned short* __restrict__ Wc,
              const unsigned short* __restrict__ W2t, const unsigned short* __restrict__ W3t,
              const unsigned short* __restrict__ W4t,
              float* __restrict__ out)
{
  __shared__ unsigned short actA[BM * SA];
  __shared__ unsigned short actB[BM * SB];
  __shared__ float crosspart[4][BM];
  __shared__ float part[BM][8];
  __shared__ float linrow[BM];

  const int t = threadIdx.x;
  const int lane = t & 63, wave = t >> 6;
  const int m = lane & 15, qd = lane >> 4;
  const int r = t >> 3, c = t & 7;  // gather/final mapping: 8 threads per row

  // ---- gather + linear + q-partials (q = sum x^2 * rowsum(K^2)) ----
  {
    int g = blockIdx.x * BM + r;
    int u = uidx[g], it = iidx[g];
    const float* up = uemb + (long)u * EMBD + c * 8;
    const float* ip = iemb + (long)it * EMBD + c * 8;
    float qp = 0.f;
#pragma unroll
    for (int j = 0; j < 8; j += 4) {
      float4 f = *(const float4*)(up + j);
      int col = c * 8 + j;
      float4 sv = *(const float4*)(S + col);
      ushortx4 h = {f2bf(f.x), f2bf(f.y), f2bf(f.z), f2bf(f.w)};
      *(ushortx4*)&actA[r * SA + col] = h;
      qp += f.x * f.x * sv.x + f.y * f.y * sv.y + f.z * f.z * sv.z + f.w * f.w * sv.w;
    }
#pragma unroll
    for (int j = 0; j < 8; j += 4) {
      float4 f = *(const float4*)(ip + j);
      int col = 64 + c * 8 + j;
      float4 sv = *(const float4*)(S + col);
      ushortx4 h = {f2bf(f.x), f2bf(f.y), f2bf(f.z), f2bf(f.w)};
      *(ushortx4*)&actA[r * SA + col] = h;
      qp += f.x * f.x * sv.x + f.y * f.y * sv.y + f.z * f.z * sv.z + f.w * f.w * sv.w;
    }
    part[r][c] = qp;
    if (c == 0) linrow[r] = linw[u] + linw[HASH_BINS + it] + linb[0];
  }
  __syncthreads();  // B1: emb in actA

  // ---- fused layer (K=128, reads actA): cross (tiles 0-7) + L1 (tiles 8-21) -> actB ----
  // waves 0-3: 2 cross tiles + 1 L1 tile; wave4: L1 {4,5,6}; wave5: L1 {7,8,9};
  // wave6: L1 {10,11}; wave7: L1 {12,13}.
  if (wave < 4) {
    floatx4 acc[8];
    mfma_pass<128, 2>(Wc, (2 * wave) * 16, actA, SA, m, qd, acc);
    // cross: per-row sum of xk^2 over this wave's 2 tiles (neuron dim = qd,reg)
    float s[4];
#pragma unroll
    for (int rt = 0; rt < 4; rt++) {
      s[rt] = 0.f;
#pragma unroll
      for (int n = 0; n < 2; n++)
#pragma unroll
        for (int i = 0; i < 4; i++)
          s[rt] += acc[n * 4 + rt][i] * acc[n * 4 + rt][i];
      s[rt] += __shfl_xor(s[rt], 16, 64);
      s[rt] += __shfl_xor(s[rt], 32, 64);
    }
    if (qd == 0)
#pragma unroll
      for (int rt = 0; rt < 4; rt++)
        crosspart[wave][rt * 16 + m] = s[rt];
    floatx4 acc2[4];
    mfma_pass<128, 1>(Wc, 128 + wave * 16, actA, SA, m, qd, acc2);
    epilogue_relu<1>(b1, wave * 16, 200, actB, SB, m, qd, acc2);
  } else if (wave < 6) {
    int s0 = 4 + (wave - 4) * 3;  // 4 or 7
    floatx4 acc[12];
    mfma_pass<128, 3>(Wc, 128 + s0 * 16, actA, SA, m, qd, acc);
    epilogue_relu<3>(b1, s0 * 16, 200, actB, SB, m, qd, acc);
  } else {
    int s0 = 10 + (wave - 6) * 2;  // 10 or 12
    floatx4 acc[8];
    mfma_pass<128, 2>(Wc, 128 + s0 * 16, actA, SA, m, qd, acc);
    epilogue_relu<2>(b1, s0 * 16, 200, actB, SB, m, qd, acc);
  }
  __syncthreads();  // B2: L1 out (224 cols, zero-padded) in actB

  // ---- W2: K=224, actB -> actA, 16 tiles, 2 per wave ----
  {
    floatx4 acc[8];
    mfma_pass<224, 2>(W2t, wave * 2 * 16, actB, SB, m, qd, acc);
    epilogue_relu<2>(b2, wave * 2 * 16, 256, actA, SA, m, qd, acc);
  }
  __syncthreads();  // B3: W2 out (256) in actA

  // ---- W3: K=256, actA -> actB, 14 tiles: waves 0-5 get 2, waves 6-7 get 1 ----
  if (wave < 6) {
    floatx4 acc[8];
    mfma_pass<256, 2>(W3t, wave * 2 * 16, actA, SA, m, qd, acc);
    epilogue_relu<2>(b3, wave * 2 * 16, 200, actB, SB, m, qd, acc);
  } else {
    int s0 = 12 + (wave - 6);
    floatx4 acc[4];
    mfma_pass<256, 1>(W3t, s0 * 16, actA, SA, m, qd, acc);
    epilogue_relu<1>(b3, s0 * 16, 200, actB, SB, m, qd, acc);
  }
  __syncthreads();  // B4: W3 out (224, zero-padded) in actB

  // ---- W4: K=224, actB -> actA, 8 tiles, 1 per wave ----
  {
    floatx4 acc[4];
    mfma_pass<224, 1>(W4t, wave * 16, actB, SB, m, qd, acc);
    epilogue_relu<1>(b4, wave * 16, 128, actA, SA, m, qd, acc);
  }
  __syncthreads();  // B5: W4 out (128) in actA

  // ---- final: W5 dot + cross combine + sigmoid ----
  {
    float qp = part[r][c];  // q-partial from gather phase (same thread wrote it)
    float d = 0.f;
    const unsigned short* ap = &actA[r * SA + c * 16];
#pragma unroll
    for (int j = 0; j < 2; j++) {
      short8 h = *(const short8*)(ap + j * 8);
      float4 w0 = *(const float4*)(W5 + c * 16 + j * 8);
      float4 w1 = *(const float4*)(W5 + c * 16 + j * 8 + 4);
      d += bf2f((unsigned short)h[0]) * w0.x + bf2f((unsigned short)h[1]) * w0.y +
           bf2f((unsigned short)h[2]) * w0.z + bf2f((unsigned short)h[3]) * w0.w +
           bf2f((unsigned short)h[4]) * w1.x + bf2f((unsigned short)h[5]) * w1.y +
           bf2f((unsigned short)h[6]) * w1.z + bf2f((unsigned short)h[7]) * w1.w;
    }
    const float inv = 0.5f / 128.f;
    part[r][c] = d - inv * qp;  // dnn partial minus q share of cross
    __syncthreads();
    if (c == 0) {
      float xk2 = crosspart[0][r] + crosspart[1][r] + crosspart[2][r] + crosspart[3][r];
      float dnn = part[r][0] + part[r][1] + part[r][2] + part[r][3] +
                  part[r][4] + part[r][5] + part[r][6] + part[r][7];
      float logit = linrow[r] + inv * xk2 + dnn + b5[0];
      out[blockIdx.x * BM + r] = 1.f / (1.f + expf(-logit));
    }
  }
}

extern "C" void kernel_launch(void* const* d_in, const int* in_sizes, int n_in,
                              void* d_out, int out_size, void* d_ws, size_t ws_size,
                              hipStream_t stream)
{
  const int*   uidx = (const int*)d_in[0];
  const int*   iidx = (const int*)d_in[1];
  const float* uemb = (const float*)d_in[2];
  const float* iemb = (const float*)d_in[3];
  const float* linw = (const float*)d_in[4];
  const float* linb = (const float*)d_in[5];
  const float* K    = (const float*)d_in[6];
  const float* W1   = (const float*)d_in[7];
  const float* b1   = (const float*)d_in[8];
  const float* W2   = (const float*)d_in[9];
  const float* b2   = (const float*)d_in[10];
  const float* W3   = (const float*)d_in[11];
  const float* b3   = (const float*)d_in[12];
  const float* W4   = (const float*)d_in[13];
  const float* b4   = (const float*)d_in[14];
  const float* W5   = (const float*)d_in[15];
  const float* b5   = (const float*)d_in[16];

  char* w = (char*)d_ws;
  float* S = (float*)w;
  unsigned short* Kt  = (unsigned short*)(w + 512);
  unsigned short* W1t = (unsigned short*)(w + 33280);
  unsigned short* W2t = (unsigned short*)(w + 90624);
  unsigned short* W3t = (unsigned short*)(w + 205312);
  unsigned short* W4t = (unsigned short*)(w + 320000);
  float* out = (float*)d_out;

  dfm_prep<<<736, 256, 0, stream>>>(K, W1, W2, W3, W4, S, Kt, W1t, W2t, W3t, W4t);
  dfm_main<<<BATCH / BM, 512, 0, stream>>>(uidx, iidx, uemb, iemb, linw, linb,
                                           b1, b2, b3, b4, W5, b5,
                                           S, Kt, W2t, W3t, W4t, out);
}

// Round 9
// 278.364 us; speedup vs baseline: 1.4890x; 1.0473x over previous
//
#include <hip/hip_runtime.h>

#define HASH_BINS 100000
#define EMBD 64
#define BATCH 262144
#define BM 64
#define SA 264  // act buffer A stride (bf16 elems)
#define SB 232  // act buffer B stride (bf16 elems)

typedef __attribute__((ext_vector_type(8))) short short8;
typedef __attribute__((ext_vector_type(4))) float floatx4;
typedef __attribute__((ext_vector_type(4))) unsigned short ushortx4;

static __device__ __forceinline__ unsigned short f2bf(float f) {
  unsigned u = __builtin_bit_cast(unsigned, f);
  u += 0x7fff + ((u >> 16) & 1);  // round-to-nearest-even
  return (unsigned short)(u >> 16);
}
static __device__ __forceinline__ float bf2f(unsigned short b) {
  return __builtin_bit_cast(float, ((unsigned)b) << 16);
}

// ---------------- prep: build bf16 transposed/padded weights in ws ----------------
// DEST-MAJOR: consecutive threads write consecutive dest quads (8B packed stores).
// Source reads scatter but hit L2 (sources < 1 MB total).
// ws layout unchanged: S@0, Kt@512 (128x128), W1t@33280 (224x128),
// W2t@90624 (256x224), W3t@205312 (224x256), W4t@320000 (128x224).
__global__ void dfm_prep(const float* __restrict__ K, const float* __restrict__ W1,
                         const float* __restrict__ W2, const float* __restrict__ W3,
                         const float* __restrict__ W4,
                         float* __restrict__ S, unsigned short* __restrict__ Kt,
                         unsigned short* __restrict__ W1t, unsigned short* __restrict__ W2t,
                         unsigned short* __restrict__ W3t, unsigned short* __restrict__ W4t)
{
  int i = blockIdx.x * 256 + threadIdx.x;
  if (i < 4096) {                          // Kt [128][128] <- K[k][n]
    int n = i >> 5, k4 = (i & 31) * 4;
    ushortx4 h = { f2bf(K[(k4 + 0) * 128 + n]), f2bf(K[(k4 + 1) * 128 + n]),
                   f2bf(K[(k4 + 2) * 128 + n]), f2bf(K[(k4 + 3) * 128 + n]) };
    *(ushortx4*)&Kt[n * 128 + k4] = h;
  } else if ((i -= 4096) < 7168) {         // W1t [224][128] <- W1[k][n], n<200
    int n = i >> 5, k4 = (i & 31) * 4;
    ushortx4 h;
#pragma unroll
    for (int j = 0; j < 4; j++) h[j] = (n < 200) ? f2bf(W1[(k4 + j) * 200 + n]) : 0;
    *(ushortx4*)&W1t[n * 128 + k4] = h;
  } else if ((i -= 7168) < 14336) {        // W2t [256][224] <- W2[k][n], k<200
    int n = i / 56, k4 = (i - n * 56) * 4;
    ushortx4 h;
#pragma unroll
    for (int j = 0; j < 4; j++) h[j] = (k4 + j < 200) ? f2bf(W2[(k4 + j) * 256 + n]) : 0;
    *(ushortx4*)&W2t[n * 224 + k4] = h;
  } else if ((i -= 14336) < 14336) {       // W3t [224][256] <- W3[k][n], n<200
    int n = i >> 6, k4 = (i & 63) * 4;
    ushortx4 h;
#pragma unroll
    for (int j = 0; j < 4; j++) h[j] = (n < 200) ? f2bf(W3[(k4 + j) * 200 + n]) : 0;
    *(ushortx4*)&W3t[n * 256 + k4] = h;
  } else if ((i -= 14336) < 7168) {        // W4t [128][224] <- W4[k][n], k<200
    int n = i / 56, k4 = (i - n * 56) * 4;
    ushortx4 h;
#pragma unroll
    for (int j = 0; j < 4; j++) h[j] = (k4 + j < 200) ? f2bf(W4[(k4 + j) * 128 + n]) : 0;
    *(ushortx4*)&W4t[n * 224 + k4] = h;
  } else if ((i -= 7168) < 128) {          // S = rowsum(K^2)
    float s = 0.f;
    for (int j = 0; j < 128; j++) { float v = K[i * 128 + j]; s += v * v; }
    S[i] = s;
  }
}

// ---- prefetch first-ks weight fragments (issued BEFORE the barrier) ----
template <int KP, int CH>
static __device__ __forceinline__ void wpref(const unsigned short* __restrict__ wt,
                                             int tileRow0, int m, int qd, short8* wpre)
{
#pragma unroll
  for (int n = 0; n < CH; n++)
    wpre[n] = *(const short8*)&wt[(tileRow0 + n * 16 + m) * KP + qd * 8];
}

// ---- MFMA pass: CH col-tiles x 4 row-tiles (ALL 64 rows), K=KP ----
// lane (m,qd,reg) holds D[neuron = tile*16 + qd*4 + reg][row = rt*16 + m].
// ks=0 weight fragments come prefetched (loaded before the preceding barrier).
template <int KP, int CH>
static __device__ __forceinline__ void mfma_pass_pre(const unsigned short* __restrict__ wt,
                                                     int tileRow0, const unsigned short* actIn,
                                                     int sin, int m, int qd, floatx4* acc,
                                                     const short8* wpre)
{
#pragma unroll
  for (int i = 0; i < CH * 4; i++) acc[i] = {0.f, 0.f, 0.f, 0.f};
  short8 a[4];
#pragma unroll
  for (int rt = 0; rt < 4; rt++)
    a[rt] = *(const short8*)&actIn[(rt * 16 + m) * sin + qd * 8];
#pragma unroll
  for (int n = 0; n < CH; n++)
#pragma unroll
    for (int rt = 0; rt < 4; rt++)
      acc[n * 4 + rt] = __builtin_amdgcn_mfma_f32_16x16x32_bf16(wpre[n], a[rt], acc[n * 4 + rt], 0, 0, 0);
#pragma unroll
  for (int ks = 1; ks < KP / 32; ks++) {
#pragma unroll
    for (int rt = 0; rt < 4; rt++)
      a[rt] = *(const short8*)&actIn[(rt * 16 + m) * sin + ks * 32 + qd * 8];
#pragma unroll
    for (int n = 0; n < CH; n++) {
      short8 w = *(const short8*)&wt[(tileRow0 + n * 16 + m) * KP + ks * 32 + qd * 8];
#pragma unroll
      for (int rt = 0; rt < 4; rt++)
        acc[n * 4 + rt] = __builtin_amdgcn_mfma_f32_16x16x32_bf16(w, a[rt], acc[n * 4 + rt], 0, 0, 0);
    }
  }
}

// non-prefetched variant (for the second pass of the fused layer)
template <int KP, int CH>
static __device__ __forceinline__ void mfma_pass(const unsigned short* __restrict__ wt,
                                                 int tileRow0, const unsigned short* actIn,
                                                 int sin, int m, int qd, floatx4* acc)
{
#pragma unroll
  for (int i = 0; i < CH * 4; i++) acc[i] = {0.f, 0.f, 0.f, 0.f};
#pragma unroll
  for (int ks = 0; ks < KP / 32; ks++) {
    short8 a[4];
#pragma unroll
    for (int rt = 0; rt < 4; rt++)
      a[rt] = *(const short8*)&actIn[(rt * 16 + m) * sin + ks * 32 + qd * 8];
#pragma unroll
    for (int n = 0; n < CH; n++) {
      short8 w = *(const short8*)&wt[(tileRow0 + n * 16 + m) * KP + ks * 32 + qd * 8];
#pragma unroll
      for (int rt = 0; rt < 4; rt++)
        acc[n * 4 + rt] = __builtin_amdgcn_mfma_f32_16x16x32_bf16(w, a[rt], acc[n * 4 + rt], 0, 0, 0);
    }
  }
}

// ---- epilogue: bias + relu, packed 8B stores (4 consecutive cols per lane) ----
template <int CH>
static __device__ __forceinline__ void epilogue_relu(const float* __restrict__ bias,
                                                     int colBase, int nreal,
                                                     unsigned short* actOut, int sout,
                                                     int m, int qd, const floatx4* acc)
{
#pragma unroll
  for (int n = 0; n < CH; n++) {
    int col = colBase + n * 16 + qd * 4;
    float b0 = 0.f, b1 = 0.f, b2 = 0.f, b3 = 0.f;
    if (col < nreal) {
      float4 q = *(const float4*)(bias + col);
      b0 = q.x; b1 = q.y; b2 = q.z; b3 = q.w;
    }
#pragma unroll
    for (int rt = 0; rt < 4; rt++) {
      ushortx4 h = { f2bf(fmaxf(acc[n * 4 + rt][0] + b0, 0.f)),
                     f2bf(fmaxf(acc[n * 4 + rt][1] + b1, 0.f)),
                     f2bf(fmaxf(acc[n * 4 + rt][2] + b2, 0.f)),
                     f2bf(fmaxf(acc[n * 4 + rt][3] + b3, 0.f)) };
      *(ushortx4*)&actOut[(rt * 16 + m) * sout + col] = h;
    }
  }
}

// ---------------- fused main kernel ----------------
__global__ __launch_bounds__(512)
void dfm_main(const int* __restrict__ uidx, const int* __restrict__ iidx,
              const float* __restrict__ uemb, const float* __restrict__ iemb,
              const float* __restrict__ linw, const float* __restrict__ linb,
              const float* __restrict__ b1, const float* __restrict__ b2,
              const float* __restrict__ b3, const float* __restrict__ b4,
              const float* __restrict__ W5, const float* __restrict__ b5,
              const float* __restrict__ S, const unsigned short* __restrict__ Wc,
              const unsigned short* __restrict__ W2t, const unsigned short* __restrict__ W3t,
              const unsigned short* __restrict__ W4t,
              float* __restrict__ out)
{
  __shared__ unsigned short actA[BM * SA];
  __shared__ unsigned short actB[BM * SB];
  __shared__ float crosspart[4][BM];
  __shared__ float part[BM][8];
  __shared__ float qpart[BM][8];
  __shared__ float linrow[BM];

  const int t = threadIdx.x;
  const int lane = t & 63, wave = t >> 6;
  const int m = lane & 15, qd = lane >> 4;
  const int r = t >> 3, c = t & 7;

  // ---- gather + linear + q-partials ----
  {
    int g = blockIdx.x * BM + r;
    int u = uidx[g], it = iidx[g];
    const float* up = uemb + (long)u * EMBD + c * 8;
    const float* ip = iemb + (long)it * EMBD + c * 8;
    float qp = 0.f;
#pragma unroll
    for (int j = 0; j < 8; j += 4) {
      float4 f = *(const float4*)(up + j);
      int col = c * 8 + j;
      float4 sv = *(const float4*)(S + col);
      ushortx4 h = {f2bf(f.x), f2bf(f.y), f2bf(f.z), f2bf(f.w)};
      *(ushortx4*)&actA[r * SA + col] = h;
      qp += f.x * f.x * sv.x + f.y * f.y * sv.y + f.z * f.z * sv.z + f.w * f.w * sv.w;
    }
#pragma unroll
    for (int j = 0; j < 8; j += 4) {
      float4 f = *(const float4*)(ip + j);
      int col = 64 + c * 8 + j;
      float4 sv = *(const float4*)(S + col);
      ushortx4 h = {f2bf(f.x), f2bf(f.y), f2bf(f.z), f2bf(f.w)};
      *(ushortx4*)&actA[r * SA + col] = h;
      qp += f.x * f.x * sv.x + f.y * f.y * sv.y + f.z * f.z * sv.z + f.w * f.w * sv.w;
    }
    qpart[r][c] = qp;
    if (c == 0) linrow[r] = linw[u] + linw[HASH_BINS + it] + linb[0];
  }

  short8 wpre[3];
  // prefetch fused-layer first-ks weight frags BEFORE the barrier
  if (wave < 4)      wpref<128, 2>(Wc, 2 * wave * 16, m, qd, wpre);
  else if (wave < 6) wpref<128, 3>(Wc, 128 + (4 + (wave - 4) * 3) * 16, m, qd, wpre);
  else               wpref<128, 2>(Wc, 128 + (10 + (wave - 6) * 2) * 16, m, qd, wpre);
  __syncthreads();  // B1: emb in actA

  // ---- fused layer (K=128): cross (tiles 0-7) + L1 (tiles 8-21) -> actB ----
  if (wave < 4) {
    floatx4 acc[8];
    mfma_pass_pre<128, 2>(Wc, 2 * wave * 16, actA, SA, m, qd, acc, wpre);
    float s[4];
#pragma unroll
    for (int rt = 0; rt < 4; rt++) {
      s[rt] = 0.f;
#pragma unroll
      for (int n = 0; n < 2; n++)
#pragma unroll
        for (int i = 0; i < 4; i++)
          s[rt] += acc[n * 4 + rt][i] * acc[n * 4 + rt][i];
      s[rt] += __shfl_xor(s[rt], 16, 64);
      s[rt] += __shfl_xor(s[rt], 32, 64);
    }
    if (qd == 0)
#pragma unroll
      for (int rt = 0; rt < 4; rt++)
        crosspart[wave][rt * 16 + m] = s[rt];
    floatx4 acc2[4];
    mfma_pass<128, 1>(Wc, 128 + wave * 16, actA, SA, m, qd, acc2);
    epilogue_relu<1>(b1, wave * 16, 200, actB, SB, m, qd, acc2);
  } else if (wave < 6) {
    int s0 = 4 + (wave - 4) * 3;
    floatx4 acc[12];
    mfma_pass_pre<128, 3>(Wc, 128 + s0 * 16, actA, SA, m, qd, acc, wpre);
    epilogue_relu<3>(b1, s0 * 16, 200, actB, SB, m, qd, acc);
  } else {
    int s0 = 10 + (wave - 6) * 2;
    floatx4 acc[8];
    mfma_pass_pre<128, 2>(Wc, 128 + s0 * 16, actA, SA, m, qd, acc, wpre);
    epilogue_relu<2>(b1, s0 * 16, 200, actB, SB, m, qd, acc);
  }
  wpref<224, 2>(W2t, wave * 32, m, qd, wpre);
  __syncthreads();  // B2: L1 out in actB

  // ---- W2: K=224, actB -> actA, 16 tiles, 2 per wave ----
  {
    floatx4 acc[8];
    mfma_pass_pre<224, 2>(W2t, wave * 32, actB, SB, m, qd, acc, wpre);
    epilogue_relu<2>(b2, wave * 32, 256, actA, SA, m, qd, acc);
  }
  if (wave < 6) wpref<256, 2>(W3t, wave * 32, m, qd, wpre);
  else          wpref<256, 1>(W3t, (12 + (wave - 6)) * 16, m, qd, wpre);
  __syncthreads();  // B3: W2 out in actA

  // ---- W3: K=256, actA -> actB, 14 tiles {2,2,2,2,2,2,1,1} ----
  if (wave < 6) {
    floatx4 acc[8];
    mfma_pass_pre<256, 2>(W3t, wave * 32, actA, SA, m, qd, acc, wpre);
    epilogue_relu<2>(b3, wave * 32, 200, actB, SB, m, qd, acc);
  } else {
    int s0 = (12 + (wave - 6)) * 16;
    floatx4 acc[4];
    mfma_pass_pre<256, 1>(W3t, s0, actA, SA, m, qd, acc, wpre);
    epilogue_relu<1>(b3, s0, 200, actB, SB, m, qd, acc);
  }
  wpref<224, 1>(W4t, wave * 16, m, qd, wpre);
  __syncthreads();  // B4: W3 out in actB

  // ---- W4 + W5 fold, all in registers: wave w owns neurons w*16..w*16+15 ----
  {
    floatx4 acc[4];
    mfma_pass_pre<224, 1>(W4t, wave * 16, actB, SB, m, qd, acc, wpre);
    int nb = wave * 16 + qd * 4;
    float4 w5q = *(const float4*)(W5 + nb);
    float4 b4q = *(const float4*)(b4 + nb);
#pragma unroll
    for (int rt = 0; rt < 4; rt++) {
      float s = fmaxf(acc[rt][0] + b4q.x, 0.f) * w5q.x +
                fmaxf(acc[rt][1] + b4q.y, 0.f) * w5q.y +
                fmaxf(acc[rt][2] + b4q.z, 0.f) * w5q.z +
                fmaxf(acc[rt][3] + b4q.w, 0.f) * w5q.w;
      s += __shfl_xor(s, 16, 64);
      s += __shfl_xor(s, 32, 64);
      if (qd == 0) part[rt * 16 + m][wave] = s;
    }
  }
  __syncthreads();  // B5: partials ready

  // ---- combine + sigmoid (wave 0) ----
  if (t < BM) {
    int rr = t;
    float xk2 = crosspart[0][rr] + crosspart[1][rr] + crosspart[2][rr] + crosspart[3][rr];
    float qs = qpart[rr][0] + qpart[rr][1] + qpart[rr][2] + qpart[rr][3] +
               qpart[rr][4] + qpart[rr][5] + qpart[rr][6] + qpart[rr][7];
    float dnn = part[rr][0] + part[rr][1] + part[rr][2] + part[rr][3] +
                part[rr][4] + part[rr][5] + part[rr][6] + part[rr][7];
    const float inv = 0.5f / 128.f;
    float logit = linrow[rr] + inv * (xk2 - qs) + dnn + b5[0];
    out[blockIdx.x * BM + rr] = 1.f / (1.f + expf(-logit));
  }
}

extern "C" void kernel_launch(void* const* d_in, const int* in_sizes, int n_in,
                              void* d_out, int out_size, void* d_ws, size_t ws_size,
                              hipStream_t stream)
{
  const int*   uidx = (const int*)d_in[0];
  const int*   iidx = (const int*)d_in[1];
  const float* uemb = (const float*)d_in[2];
  const float* iemb = (const float*)d_in[3];
  const float* linw = (const float*)d_in[4];
  const float* linb = (const float*)d_in[5];
  const float* K    = (const float*)d_in[6];
  const float* W1   = (const float*)d_in[7];
  const float* b1   = (const float*)d_in[8];
  const float* W2   = (const float*)d_in[9];
  const float* b2   = (const float*)d_in[10];
  const float* W3   = (const float*)d_in[11];
  const float* b3   = (const float*)d_in[12];
  const float* W4   = (const float*)d_in[13];
  const float* b4   = (const float*)d_in[14];
  const float* W5   = (const float*)d_in[15];
  const float* b5   = (const float*)d_in[16];

  char* w = (char*)d_ws;
  float* S = (float*)w;
  unsigned short* Kt  = (unsigned short*)(w + 512);
  unsigned short* W1t = (unsigned short*)(w + 33280);
  unsigned short* W2t = (unsigned short*)(w + 90624);
  unsigned short* W3t = (unsigned short*)(w + 205312);
  unsigned short* W4t = (unsigned short*)(w + 320000);
  float* out = (float*)d_out;

  dfm_prep<<<185, 256, 0, stream>>>(K, W1, W2, W3, W4, S, Kt, W1t, W2t, W3t, W4t);
  dfm_main<<<BATCH / BM, 512, 0, stream>>>(uidx, iidx, uemb, iemb, linw, linb,
                                           b1, b2, b3, b4, W5, b5,
                                           S, Kt, W2t, W3t, W4t, out);
}